// Round 5
// baseline (121.442 us; speedup 1.0000x reference)
//
#include <hip/hip_runtime.h>
#include <math.h>

// ---------------------------------------------------------------------------
// CAM module, fused MFMA version (hi/lo-bf16 throughout the q/k/energy path).
//   k_prep:        [Wq;Wk] -> tiled hi/lo bf16 (staging = pure uint4 copies)
//   k_conv_energy: C=[Wq;Wk]@P per 64-col tile (split-bf16, 3 MFMA/frag,
//                  software-pipelined global->reg prefetch)
//                  -> repack C+bias to hi/lo bf16 LDS (XOR swizzle)
//                  -> epart[b][nt] = q_tile @ k_tile^T  (q/k never hit HBM)
//   k_softmax_M:   reduce 64 partials, softmax(rowmin-e), M=A@Wv, ob=A@bv
//   k_out:         out = M @ X + ob   (plain bf16 MFMA, HBM-bound)
// Numerics: fp16/bf16-RTN on q/k path FAILS (R4: absmax 0.203) — logit error
// budget is ~5e-3, only hi/lo split (eps~2^-17 -> d_e~1e-3) meets it.
// ---------------------------------------------------------------------------

typedef float f32x4 __attribute__((ext_vector_type(4)));
typedef short s16x8 __attribute__((ext_vector_type(8)));

__device__ __forceinline__ unsigned short f2bf(float f) {
  union { float f; unsigned u; } v; v.f = f;
  unsigned r = v.u + 0x7FFFu + ((v.u >> 16) & 1u);
  return (unsigned short)(r >> 16);
}
__device__ __forceinline__ float bf2f(unsigned short h) {
  union { unsigned u; float f; } v; v.u = ((unsigned)h) << 16;
  return v.f;
}

// ---------------- Kernel 0: W -> tiled hi/lo bf16 --------------------------
// Wt[step][row][koff], step = k/32; 16*256*32 u16 per plane. grid 128x256.
__global__ __launch_bounds__(256) void k_prep(
    const float* __restrict__ Wq, const float* __restrict__ Wk,
    unsigned short* __restrict__ Wth, unsigned short* __restrict__ Wtl) {
  const int f = (blockIdx.x * 256 + threadIdx.x) * 4;
  const int row = f >> 9;
  const int k   = f & 511;
  const float* src = (row < 128) ? &Wq[row * 512 + k] : &Wk[(row - 128) * 512 + k];
  float4 v = *(const float4*)src;
  unsigned short h0 = f2bf(v.x), h1 = f2bf(v.y), h2 = f2bf(v.z), h3 = f2bf(v.w);
  unsigned short l0 = f2bf(v.x - bf2f(h0)), l1 = f2bf(v.y - bf2f(h1));
  unsigned short l2 = f2bf(v.z - bf2f(h2)), l3 = f2bf(v.w - bf2f(h3));
  const int di = (k >> 5) * 8192 + row * 32 + (k & 31);
  *(ushort4*)&Wth[di] = make_ushort4(h0, h1, h2, h3);
  *(ushort4*)&Wtl[di] = make_ushort4(l0, l1, l2, l3);
}

// ---------------- Kernel 1: fused conv + energy partial --------------------
// grid (64 nt, 8 b), 256 thr = 4 waves. Tile rows 0-255 (q:0-127,k:128-255),
// cols nt*64..+63, K=512 in 16 steps of 32 (split-bf16, 3 MFMA/frag),
// global->reg prefetch one step ahead.
__global__ __launch_bounds__(256, 2) void k_conv_energy(
    const float* __restrict__ x,
    const unsigned short* __restrict__ Wth, const unsigned short* __restrict__ Wtl,
    const float* __restrict__ bq, const float* __restrict__ bk,
    float* __restrict__ epart) {
  __shared__ unsigned short LDS[32768];   // 64 KiB, unioned across phases
  unsigned short* Ah = LDS;               // 256*40 (conv phase)
  unsigned short* Al = LDS + 10240;       // 256*40
  unsigned short* Bh = LDS + 20480;       // 64*40
  unsigned short* Bl = LDS + 23040;       // 64*40
  unsigned short* Th = LDS;               // 256*64 (energy phase, hi)
  unsigned short* Tl = LDS + 16384;       // 256*64 (lo)

  const int t = threadIdx.x;
  const int nt = blockIdx.x, b = blockIdx.y;
  const int w = t >> 6, lane = t & 63;
  const int lrow = lane & 15, lkb = lane >> 4;

  // B staging map: thread -> (ci_ = t>>5, 4 x-cols at c0, both kh rows)
  const int ci_ = t >> 5;            // 0..7
  const int c0 = (t & 31) * 4;       // x-col offset
  const int n0 = c0 >> 1;            // output col (even)
  const int gB = ci_ >> 1;           // logical 16B-chunk (8 u16) 0..3
  const int halfB = (ci_ & 1) * 4;   // u16 offset within chunk
  const int gsB = gB ^ ((n0 >> 2) & 3);  // XOR-swizzled chunk position
  const float* xb = x + ((size_t)b << 21);

  f32x4 acc[4][4];
#pragma unroll
  for (int m = 0; m < 4; ++m)
#pragma unroll
    for (int n = 0; n < 4; ++n) acc[m][n] = (f32x4){0.f, 0.f, 0.f, 0.f};

  // -------- prologue: prefetch step 0 into regs ---------------------------
  uint4 pah[4], pal[4];
  float4 pb0, pb1;
  {
    const uint4* gh = (const uint4*)Wth;
    const uint4* gl = (const uint4*)Wtl;
#pragma unroll
    for (int j = 0; j < 4; ++j) { pah[j] = gh[t + 256 * j]; pal[j] = gl[t + 256 * j]; }
    const float* xr = xb + (size_t)ci_ * 16384 + (2 * nt) * 128 + c0;
    pb0 = *(const float4*)xr;
    pb1 = *(const float4*)(xr + 128);
  }

  for (int step = 0; step < 16; ++step) {
    // ---- write staged regs to LDS ----
#pragma unroll
    for (int j = 0; j < 4; ++j) {
      const int c = t + 256 * j;
      const int row = c >> 2, ko = (c & 3) * 8;
      *(uint4*)&Ah[row * 40 + ko] = pah[j];
      *(uint4*)&Al[row * 40 + ko] = pal[j];
    }
    {
      // k-order within chunk: (ci&1)*4 + kh*2 + kw
      const float e0[4] = {pb0.x, pb0.y, pb1.x, pb1.y};   // col n0
      const float e1[4] = {pb0.z, pb0.w, pb1.z, pb1.w};   // col n0+1
      ushort4 h0, l0, h1, l1;
#pragma unroll
      for (int i = 0; i < 4; ++i) {
        const unsigned short a = f2bf(e0[i]);
        ((unsigned short*)&h0)[i] = a;
        ((unsigned short*)&l0)[i] = f2bf(e0[i] - bf2f(a));
        const unsigned short bshort = f2bf(e1[i]);
        ((unsigned short*)&h1)[i] = bshort;
        ((unsigned short*)&l1)[i] = f2bf(e1[i] - bf2f(bshort));
      }
      const int a0 = n0 * 40 + gsB * 8 + halfB;
      const int a1 = (n0 + 1) * 40 + gsB * 8 + halfB;
      *(ushort4*)&Bh[a0] = h0;
      *(ushort4*)&Bl[a0] = l0;
      *(ushort4*)&Bh[a1] = h1;
      *(ushort4*)&Bl[a1] = l1;
    }
    __syncthreads();
    // ---- prefetch step+1 (lands during MFMA below) ----
    if (step < 15) {
      const uint4* gh = (const uint4*)(Wth + (step + 1) * 8192);
      const uint4* gl = (const uint4*)(Wtl + (step + 1) * 8192);
#pragma unroll
      for (int j = 0; j < 4; ++j) { pah[j] = gh[t + 256 * j]; pal[j] = gl[t + 256 * j]; }
      const float* xr = xb + (size_t)((step + 1) * 8 + ci_) * 16384 + (2 * nt) * 128 + c0;
      pb0 = *(const float4*)xr;
      pb1 = *(const float4*)(xr + 128);
    }
    // ---- fragments + MFMA ----
    s16x8 afh[4], afl[4], bfh[4], bfl[4];
#pragma unroll
    for (int m = 0; m < 4; ++m) {
      const int aidx = (w * 64 + m * 16 + lrow) * 40 + lkb * 8;
      afh[m] = *(const s16x8*)&Ah[aidx];
      afl[m] = *(const s16x8*)&Al[aidx];
    }
#pragma unroll
    for (int nf = 0; nf < 4; ++nf) {
      const int row = nf * 16 + lrow;
      const int bidx = row * 40 + (lkb ^ ((row >> 2) & 3)) * 8;
      bfh[nf] = *(const s16x8*)&Bh[bidx];
      bfl[nf] = *(const s16x8*)&Bl[bidx];
    }
#pragma unroll
    for (int m = 0; m < 4; ++m)
#pragma unroll
      for (int n = 0; n < 4; ++n) {
        acc[m][n] = __builtin_amdgcn_mfma_f32_16x16x32_bf16(afh[m], bfh[n], acc[m][n], 0, 0, 0);
        acc[m][n] = __builtin_amdgcn_mfma_f32_16x16x32_bf16(afh[m], bfl[n], acc[m][n], 0, 0, 0);
        acc[m][n] = __builtin_amdgcn_mfma_f32_16x16x32_bf16(afl[m], bfh[n], acc[m][n], 0, 0, 0);
      }
    __syncthreads();
  }

  // ---- phase 2: repack C+bias -> hi/lo bf16 LDS tile, XOR-swizzled -------
  const float* biasp = (w < 2) ? bq : bk;
  const int rb = (w & 1) * 64;
  float biasr[16];
#pragma unroll
  for (int m = 0; m < 4; ++m)
#pragma unroll
    for (int i = 0; i < 4; ++i)
      biasr[m * 4 + i] = biasp[rb + m * 16 + (lane >> 4) * 4 + i];

#pragma unroll
  for (int m = 0; m < 4; ++m) {
    const int r0 = w * 64 + m * 16 + (lane >> 4) * 4;
#pragma unroll
    for (int n = 0; n < 4; ++n) {
      const int c = n * 16 + lrow;
      const int c8 = c >> 3, c7 = c & 7;
#pragma unroll
      for (int i = 0; i < 4; ++i) {
        const int r = r0 + i;
        const float vv = acc[m][n][i] + biasr[m * 4 + i];
        const unsigned short h = f2bf(vv);
        const unsigned short l = f2bf(vv - bf2f(h));
        const int ad = r * 64 + (((c8 ^ (r & 7))) << 3) + c7;
        Th[ad] = h;
        Tl[ad] = l;
      }
    }
  }
  __syncthreads();

  // ---- phase 3: energy partial = q_tile(128x64) @ k_tile(128x64)^T --------
  f32x4 e[4][4];
#pragma unroll
  for (int m = 0; m < 4; ++m)
#pragma unroll
    for (int n = 0; n < 4; ++n) e[m][n] = (f32x4){0.f, 0.f, 0.f, 0.f};

  const int mrow0 = (w >> 1) * 64;       // q-half rows (0 or 64)
  const int nrow0 = 128 + (w & 1) * 64;  // k-half rows
#pragma unroll
  for (int ks = 0; ks < 2; ++ks) {
    const int c8 = ks * 4 + lkb;
    s16x8 qh[4], ql[4], kh8[4], kl8[4];
#pragma unroll
    for (int m = 0; m < 4; ++m) {
      const int r = mrow0 + m * 16 + lrow;
      const int ad = r * 64 + ((c8 ^ (r & 7)) << 3);
      qh[m] = *(const s16x8*)&Th[ad];
      ql[m] = *(const s16x8*)&Tl[ad];
    }
#pragma unroll
    for (int n = 0; n < 4; ++n) {
      const int r = nrow0 + n * 16 + lrow;
      const int ad = r * 64 + ((c8 ^ (r & 7)) << 3);
      kh8[n] = *(const s16x8*)&Th[ad];
      kl8[n] = *(const s16x8*)&Tl[ad];
    }
#pragma unroll
    for (int m = 0; m < 4; ++m)
#pragma unroll
      for (int n = 0; n < 4; ++n) {
        e[m][n] = __builtin_amdgcn_mfma_f32_16x16x32_bf16(qh[m], kh8[n], e[m][n], 0, 0, 0);
        e[m][n] = __builtin_amdgcn_mfma_f32_16x16x32_bf16(qh[m], kl8[n], e[m][n], 0, 0, 0);
        e[m][n] = __builtin_amdgcn_mfma_f32_16x16x32_bf16(ql[m], kh8[n], e[m][n], 0, 0, 0);
      }
  }
  float* ep = epart + ((size_t)b * 64 + nt) * 16384;
#pragma unroll
  for (int m = 0; m < 4; ++m) {
    const int qr = (w >> 1) * 64 + m * 16 + (lane >> 4) * 4;
#pragma unroll
    for (int n = 0; n < 4; ++n) {
      const int kr = (w & 1) * 64 + n * 16 + lrow;
#pragma unroll
      for (int i = 0; i < 4; ++i) ep[(size_t)(qr + i) * 128 + kr] = e[m][n][i];
    }
  }
}

// ---------------- Kernel 2: reduce + softmax + M = A@Wv, ob = A@bv ---------
// wave per row c. grid(256): b = blk>>5, c = (blk&31)*4 + wid. 256 thr.
__global__ __launch_bounds__(256) void k_softmax_M(
    const float* __restrict__ epart, const float* __restrict__ Wv,
    const float* __restrict__ bv, float* __restrict__ Mbuf,
    float* __restrict__ outbb) {
  __shared__ float As[4][128];
  const int t = threadIdx.x;
  const int wid = t >> 6, lane = t & 63;
  const int b = blockIdx.x >> 5;
  const int c = (blockIdx.x & 31) * 4 + wid;
  const int d0 = lane * 2;

  float2 s = make_float2(0.f, 0.f);
#pragma unroll 4
  for (int p = 0; p < 64; ++p) {
    float2 e = *(const float2*)&epart[((size_t)b * 64 + p) * 16384 + c * 128 + d0];
    s.x += e.x; s.y += e.y;
  }
  float mn = fminf(s.x, s.y);
#pragma unroll
  for (int off = 1; off < 64; off <<= 1) mn = fminf(mn, __shfl_xor(mn, off));
  const float p0 = expf(mn - s.x);
  const float p1 = expf(mn - s.y);
  float tot = p0 + p1;
#pragma unroll
  for (int off = 1; off < 64; off <<= 1) tot += __shfl_xor(tot, off);
  const float inv = 1.f / tot;
  const float a0 = p0 * inv, a1 = p1 * inv;

  const float2 bvv = *(const float2*)&bv[d0];
  float ob = a0 * bvv.x + a1 * bvv.y;
#pragma unroll
  for (int off = 1; off < 64; off <<= 1) ob += __shfl_xor(ob, off);
  if (lane == 0) outbb[b * 128 + c] = ob;

  As[wid][d0] = a0;
  As[wid][d0 + 1] = a1;   // wave-local write->read, lockstep-safe
  float m0 = 0.f, m1 = 0.f;
#pragma unroll 4
  for (int d = 0; d < 128; ++d) {
    const float a = As[wid][d];
    const float2 wv = *(const float2*)&Wv[d * 128 + d0];
    m0 = fmaf(a, wv.x, m0);
    m1 = fmaf(a, wv.y, m1);
  }
  *(float2*)&Mbuf[(size_t)b * 16384 + c * 128 + d0] = make_float2(m0, m1);
}

// ---------------- Kernel 3: out = M @ X + ob, plain bf16 MFMA --------------
// grid (128 n-tiles, 8 b), 256 thr = 4 waves (2x2 of 64x64). K=128.
__global__ __launch_bounds__(256) void k_out(
    const float* __restrict__ x, const float* __restrict__ Mbuf,
    const float* __restrict__ outbb, float* __restrict__ out) {
  __shared__ unsigned short Ms[128 * 40];
  __shared__ unsigned short Xs[128 * 40];
  const int t = threadIdx.x;
  const int nt = blockIdx.x, b = blockIdx.y;
  const int wid = t >> 6, lane = t & 63;
  const int wr = wid >> 1, wc = wid & 1;
  const int lrow = lane & 15, lkb = lane >> 4;
  const int am = t >> 1, ak0 = (t & 1) * 16;
  const int xkl = (t >> 5) * 4;
  const int xc0 = (t & 31) * 4;

  const float* xb = x + ((size_t)b << 21);
  const float* Mb = Mbuf + (size_t)b * 16384;
  float* ob = out + ((size_t)b << 21);

  f32x4 acc[4][4];
#pragma unroll
  for (int m = 0; m < 4; ++m)
#pragma unroll
    for (int n = 0; n < 4; ++n) acc[m][n] = (f32x4){0.f, 0.f, 0.f, 0.f};

  for (int step = 0; step < 4; ++step) {
    const int kk = step * 32;
    {
      float w[16];
      *(float4*)&w[0]  = *(const float4*)&Mb[am * 128 + kk + ak0];
      *(float4*)&w[4]  = *(const float4*)&Mb[am * 128 + kk + ak0 + 4];
      *(float4*)&w[8]  = *(const float4*)&Mb[am * 128 + kk + ak0 + 8];
      *(float4*)&w[12] = *(const float4*)&Mb[am * 128 + kk + ak0 + 12];
      unsigned short hs[16];
#pragma unroll
      for (int i = 0; i < 16; ++i) hs[i] = f2bf(w[i]);
      *(uint4*)&Ms[am * 40 + ak0]     = *(uint4*)&hs[0];
      *(uint4*)&Ms[am * 40 + ak0 + 8] = *(uint4*)&hs[8];
    }
#pragma unroll
    for (int q = 0; q < 4; ++q) {
      const int kl = xkl + q;
      float4 v = *(const float4*)&xb[(size_t)(kk + kl) * 16384 + nt * 128 + xc0];
      Xs[(xc0 + 0) * 40 + kl] = f2bf(v.x);
      Xs[(xc0 + 1) * 40 + kl] = f2bf(v.y);
      Xs[(xc0 + 2) * 40 + kl] = f2bf(v.z);
      Xs[(xc0 + 3) * 40 + kl] = f2bf(v.w);
    }
    __syncthreads();
    s16x8 af[4], bf[4];
#pragma unroll
    for (int m = 0; m < 4; ++m)
      af[m] = *(const s16x8*)&Ms[(wr * 64 + m * 16 + lrow) * 40 + lkb * 8];
#pragma unroll
    for (int n = 0; n < 4; ++n)
      bf[n] = *(const s16x8*)&Xs[(wc * 64 + n * 16 + lrow) * 40 + lkb * 8];
#pragma unroll
    for (int m = 0; m < 4; ++m)
#pragma unroll
      for (int n = 0; n < 4; ++n)
        acc[m][n] = __builtin_amdgcn_mfma_f32_16x16x32_bf16(af[m], bf[n], acc[m][n], 0, 0, 0);
    __syncthreads();
  }
#pragma unroll
  for (int m = 0; m < 4; ++m) {
    const int r0 = wr * 64 + m * 16 + (lane >> 4) * 4;
#pragma unroll
    for (int n = 0; n < 4; ++n) {
      const int gc = nt * 128 + wc * 64 + n * 16 + (lane & 15);
#pragma unroll
      for (int i = 0; i < 4; ++i) {
        const int row = r0 + i;
        ob[(size_t)row * 16384 + gc] = acc[m][n][i] + outbb[b * 128 + row];
      }
    }
  }
}

// ---------------------------------------------------------------------------
extern "C" void kernel_launch(void* const* d_in, const int* in_sizes, int n_in,
                              void* d_out, int out_size, void* d_ws, size_t ws_size,
                              hipStream_t stream) {
  const float* x  = (const float*)d_in[0];
  const float* Wq = (const float*)d_in[1];
  const float* bq = (const float*)d_in[2];
  const float* Wk = (const float*)d_in[3];
  const float* bk = (const float*)d_in[4];
  const float* Wv = (const float*)d_in[5];
  const float* bv = (const float*)d_in[6];
  float* out = (float*)d_out;
  char* ws = (char*)d_ws;

  float* epart = (float*)ws;                               // 32 MiB
  float* Mbuf  = (float*)(ws + 33554432);                  // 512 KiB
  float* outbb = (float*)(ws + 34078720);                  // 4 KiB
  unsigned short* Wth = (unsigned short*)(ws + 34082816);  // 256 KiB
  unsigned short* Wtl = (unsigned short*)(ws + 34344960);  // 256 KiB

  hipLaunchKernelGGL(k_prep, dim3(128), dim3(256), 0, stream, Wq, Wk, Wth, Wtl);
  hipLaunchKernelGGL(k_conv_energy, dim3(64, 8), dim3(256), 0, stream,
                     x, Wth, Wtl, bq, bk, epart);
  hipLaunchKernelGGL(k_softmax_M, dim3(256), dim3(256), 0, stream,
                     epart, Wv, bv, Mbuf, outbb);
  hipLaunchKernelGGL(k_out, dim3(128, 8), dim3(256), 0, stream,
                     x, Mbuf, outbb, out);
}

// Round 7
// 87.618 us; speedup vs baseline: 1.3860x; 1.3860x over previous
//
#include <hip/hip_runtime.h>
#include <math.h>

// ---------------------------------------------------------------------------
// CAM module, fused MFMA version (hi/lo-bf16 q/k/energy path — R3 numerics).
//   k_prep:        [Wq;Wk] -> tiled hi/lo bf16, fragment-coalesced layout
//   k_conv_energy: C=[Wq;Wk]@P per 64-col tile (split-bf16, 3 MFMA/frag)
//                  A fragments loaded GLOBAL->VGPR (L2-resident, no LDS);
//                  B tile double-buffered in LDS, ONE barrier per K-step;
//                  -> repack C+bias to hi/lo bf16 LDS (XOR swizzle)
//                  -> epart[b][nt] = q_tile @ k_tile^T  (q/k never hit HBM)
//   k_softmax_M:   reduce 64 partials, softmax(rowmin-e), M=A@Wv, ob=A@bv
//   k_out:         out = M @ X + ob   (plain bf16 MFMA, HBM-bound)
// Numerics: fp16/bf16-RTN on q/k FAILS (R4: 0.203) — logit budget ~5e-3 needs
// the hi/lo split. R5 lesson: uint4 prefetch ARRAYS get demoted to LDS.
// R6 lesson: pointer ARRAYS initialized from __shared__ fail to compile
// (addrspacecast static init) — use offset arithmetic off one LDS base.
// ---------------------------------------------------------------------------

typedef float f32x4 __attribute__((ext_vector_type(4)));
typedef short s16x8 __attribute__((ext_vector_type(8)));

__device__ __forceinline__ unsigned short f2bf(float f) {
  union { float f; unsigned u; } v; v.f = f;
  unsigned r = v.u + 0x7FFFu + ((v.u >> 16) & 1u);
  return (unsigned short)(r >> 16);
}
__device__ __forceinline__ float bf2f(unsigned short h) {
  union { unsigned u; float f; } v; v.u = ((unsigned)h) << 16;
  return v.f;
}
__device__ __forceinline__ unsigned pack2(unsigned short a, unsigned short b) {
  return (unsigned)a | ((unsigned)b << 16);
}

// stage one float4 of x (cols c..c+3 = 2 output-cols x kw 0/1) into B tile
__device__ __forceinline__ void stage_pair(unsigned short* Bh, unsigned short* Bl,
                                           int nl, int kloc, float4 v) {
  unsigned short hx = f2bf(v.x), hy = f2bf(v.y), hz = f2bf(v.z), hw = f2bf(v.w);
  unsigned short lx = f2bf(v.x - bf2f(hx)), ly = f2bf(v.y - bf2f(hy));
  unsigned short lz = f2bf(v.z - bf2f(hz)), lw = f2bf(v.w - bf2f(hw));
  *(unsigned*)&Bh[nl * 40 + kloc]       = pack2(hx, hy);
  *(unsigned*)&Bh[(nl + 1) * 40 + kloc] = pack2(hz, hw);
  *(unsigned*)&Bl[nl * 40 + kloc]       = pack2(lx, ly);
  *(unsigned*)&Bl[(nl + 1) * 40 + kloc] = pack2(lz, lw);
}

// ---------------- Kernel 0: W -> tiled hi/lo bf16 --------------------------
// Wt[step][row][koff], step = k/32; 16*256*32 u16 per plane. grid 128x256.
__global__ __launch_bounds__(256) void k_prep(
    const float* __restrict__ Wq, const float* __restrict__ Wk,
    unsigned short* __restrict__ Wth, unsigned short* __restrict__ Wtl) {
  const int f = (blockIdx.x * 256 + threadIdx.x) * 4;
  const int row = f >> 9;
  const int k   = f & 511;
  const float* src = (row < 128) ? &Wq[row * 512 + k] : &Wk[(row - 128) * 512 + k];
  float4 v = *(const float4*)src;
  unsigned short h0 = f2bf(v.x), h1 = f2bf(v.y), h2 = f2bf(v.z), h3 = f2bf(v.w);
  unsigned short l0 = f2bf(v.x - bf2f(h0)), l1 = f2bf(v.y - bf2f(h1));
  unsigned short l2 = f2bf(v.z - bf2f(h2)), l3 = f2bf(v.w - bf2f(h3));
  const int di = (k >> 5) * 8192 + row * 32 + (k & 31);
  *(ushort4*)&Wth[di] = make_ushort4(h0, h1, h2, h3);
  *(ushort4*)&Wtl[di] = make_ushort4(l0, l1, l2, l3);
}

// ---------------- Kernel 1: fused conv + energy partial --------------------
// grid (64 nt, 8 b), 256 thr = 4 waves. Tile rows 0-255 (q:0-127,k:128-255),
// cols nt*64..+63, K=512 in 16 steps of 32 (split-bf16, 3 MFMA/frag).
// A fragments: direct global loads (coalesced 1KB/wave segments, L2-hot).
// B tile: LDS double-buffer (offset-arithmetic bases), one barrier per step.
__global__ __launch_bounds__(256, 2) void k_conv_energy(
    const float* __restrict__ x,
    const unsigned short* __restrict__ Wth, const unsigned short* __restrict__ Wtl,
    const float* __restrict__ bq, const float* __restrict__ bk,
    float* __restrict__ epart) {
  __shared__ unsigned short LDS[32768];   // 64 KiB, unioned across phases
  // conv phase: B double-buffer at offsets {0,2560} and {5120,7680} (u16 idx)
  // energy phase:
  unsigned short* Th = LDS;               // 256*64 (hi)
  unsigned short* Tl = LDS + 16384;       // 256*64 (lo)

  const int t = threadIdx.x;
  const int nt = blockIdx.x, b = blockIdx.y;
  const int w = t >> 6, lane = t & 63;
  const int lrow = lane & 15, lkb = lane >> 4;

  // B staging map (R3): pp=(ci_l,kh); 16 thr cover 128 x-cols of one (ci,h) row
  const int pp = t >> 4;
  const int ci_l = pp >> 1, kh = pp & 1;
  const int c0 = (t & 15) * 8;
  const int klb = ci_l * 4 + kh * 2;
  const float* xb = x + ((size_t)b << 21);
  const float* xrow = xb + (size_t)ci_l * 16384 + (2 * nt + kh) * 128 + c0;

  f32x4 acc[4][4];
#pragma unroll
  for (int m = 0; m < 4; ++m)
#pragma unroll
    for (int n = 0; n < 4; ++n) acc[m][n] = (f32x4){0.f, 0.f, 0.f, 0.f};

  // -------- prologue: stage B for step 0 into buffer 0 --------------------
  {
    float4 v1 = *(const float4*)&xrow[0];
    float4 v2 = *(const float4*)&xrow[4];
    stage_pair(LDS, LDS + 2560, c0 >> 1, klb, v1);
    stage_pair(LDS, LDS + 2560, (c0 >> 1) + 2, klb, v2);
  }
  __syncthreads();

  int cur = 0;
  for (int step = 0; step < 16; ++step) {
    // ---- issue x loads for step+1 (named float4 scalars; consumed post-MFMA)
    float4 pv1, pv2;
    if (step < 15) {
      const float* xr = xrow + (size_t)(step + 1) * 8 * 16384;
      pv1 = *(const float4*)&xr[0];
      pv2 = *(const float4*)&xr[4];
    }
    // ---- A fragments: direct global loads from tiled W (L2-resident) ----
    s16x8 afh[4], afl[4], bfh[4], bfl[4];
    {
      const unsigned short* Wh_s = Wth + step * 8192;
      const unsigned short* Wl_s = Wtl + step * 8192;
#pragma unroll
      for (int m = 0; m < 4; ++m) {
        const int off = (w * 64 + m * 16 + lrow) * 32 + lkb * 8;
        afh[m] = *(const s16x8*)&Wh_s[off];
        afl[m] = *(const s16x8*)&Wl_s[off];
      }
    }
    // ---- B fragments from LDS buffer[cur] ----
    const unsigned short* Bh = LDS + cur * 5120;
    const unsigned short* Bl = Bh + 2560;
#pragma unroll
    for (int nf = 0; nf < 4; ++nf) {
      const int bidx = (nf * 16 + lrow) * 40 + lkb * 8;
      bfh[nf] = *(const s16x8*)&Bh[bidx];
      bfl[nf] = *(const s16x8*)&Bl[bidx];
    }
    // ---- MFMA ----
#pragma unroll
    for (int m = 0; m < 4; ++m)
#pragma unroll
      for (int n = 0; n < 4; ++n) {
        acc[m][n] = __builtin_amdgcn_mfma_f32_16x16x32_bf16(afh[m], bfh[n], acc[m][n], 0, 0, 0);
        acc[m][n] = __builtin_amdgcn_mfma_f32_16x16x32_bf16(afh[m], bfl[n], acc[m][n], 0, 0, 0);
        acc[m][n] = __builtin_amdgcn_mfma_f32_16x16x32_bf16(afl[m], bfh[n], acc[m][n], 0, 0, 0);
      }
    // ---- convert + write B for step+1 into buffer[cur^1] ----
    if (step < 15) {
      unsigned short* Nh = LDS + (cur ^ 1) * 5120;
      unsigned short* Nl = Nh + 2560;
      stage_pair(Nh, Nl, c0 >> 1, klb, pv1);
      stage_pair(Nh, Nl, (c0 >> 1) + 2, klb, pv2);
    }
    __syncthreads();
    cur ^= 1;
  }

  // ---- phase 2: repack C+bias -> hi/lo bf16 LDS tile, XOR-swizzled -------
  const float* biasp = (w < 2) ? bq : bk;
  const int rb = (w & 1) * 64;
  float biasr[16];
#pragma unroll
  for (int m = 0; m < 4; ++m)
#pragma unroll
    for (int i = 0; i < 4; ++i)
      biasr[m * 4 + i] = biasp[rb + m * 16 + (lane >> 4) * 4 + i];

#pragma unroll
  for (int m = 0; m < 4; ++m) {
    const int r0 = w * 64 + m * 16 + (lane >> 4) * 4;
#pragma unroll
    for (int n = 0; n < 4; ++n) {
      const int c = n * 16 + lrow;
      const int c8 = c >> 3, c7 = c & 7;
#pragma unroll
      for (int i = 0; i < 4; ++i) {
        const int r = r0 + i;
        const float vv = acc[m][n][i] + biasr[m * 4 + i];
        const unsigned short h = f2bf(vv);
        const unsigned short l = f2bf(vv - bf2f(h));
        const int ad = r * 64 + (((c8 ^ (r & 7))) << 3) + c7;
        Th[ad] = h;
        Tl[ad] = l;
      }
    }
  }
  __syncthreads();

  // ---- phase 3: energy partial = q_tile(128x64) @ k_tile(128x64)^T --------
  f32x4 e[4][4];
#pragma unroll
  for (int m = 0; m < 4; ++m)
#pragma unroll
    for (int n = 0; n < 4; ++n) e[m][n] = (f32x4){0.f, 0.f, 0.f, 0.f};

  const int mrow0 = (w >> 1) * 64;       // q-half rows (0 or 64)
  const int nrow0 = 128 + (w & 1) * 64;  // k-half rows
#pragma unroll
  for (int ks = 0; ks < 2; ++ks) {
    const int c8 = ks * 4 + lkb;
    s16x8 qh[4], ql[4], kh8[4], kl8[4];
#pragma unroll
    for (int m = 0; m < 4; ++m) {
      const int r = mrow0 + m * 16 + lrow;
      const int ad = r * 64 + ((c8 ^ (r & 7)) << 3);
      qh[m] = *(const s16x8*)&Th[ad];
      ql[m] = *(const s16x8*)&Tl[ad];
    }
#pragma unroll
    for (int n = 0; n < 4; ++n) {
      const int r = nrow0 + n * 16 + lrow;
      const int ad = r * 64 + ((c8 ^ (r & 7)) << 3);
      kh8[n] = *(const s16x8*)&Th[ad];
      kl8[n] = *(const s16x8*)&Tl[ad];
    }
#pragma unroll
    for (int m = 0; m < 4; ++m)
#pragma unroll
      for (int n = 0; n < 4; ++n) {
        e[m][n] = __builtin_amdgcn_mfma_f32_16x16x32_bf16(qh[m], kh8[n], e[m][n], 0, 0, 0);
        e[m][n] = __builtin_amdgcn_mfma_f32_16x16x32_bf16(qh[m], kl8[n], e[m][n], 0, 0, 0);
        e[m][n] = __builtin_amdgcn_mfma_f32_16x16x32_bf16(ql[m], kh8[n], e[m][n], 0, 0, 0);
      }
  }
  float* ep = epart + ((size_t)b * 64 + nt) * 16384;
#pragma unroll
  for (int m = 0; m < 4; ++m) {
    const int qr = (w >> 1) * 64 + m * 16 + (lane >> 4) * 4;
#pragma unroll
    for (int n = 0; n < 4; ++n) {
      const int kr = (w & 1) * 64 + n * 16 + lrow;
#pragma unroll
      for (int i = 0; i < 4; ++i) ep[(size_t)(qr + i) * 128 + kr] = e[m][n][i];
    }
  }
}

// ---------------- Kernel 2: reduce + softmax + M = A@Wv, ob = A@bv ---------
// wave per row c. grid(256): b = blk>>5, c = (blk&31)*4 + wid. 256 thr.
__global__ __launch_bounds__(256) void k_softmax_M(
    const float* __restrict__ epart, const float* __restrict__ Wv,
    const float* __restrict__ bv, float* __restrict__ Mbuf,
    float* __restrict__ outbb) {
  __shared__ float As[4][128];
  const int t = threadIdx.x;
  const int wid = t >> 6, lane = t & 63;
  const int b = blockIdx.x >> 5;
  const int c = (blockIdx.x & 31) * 4 + wid;
  const int d0 = lane * 2;

  float2 s = make_float2(0.f, 0.f);
#pragma unroll 4
  for (int p = 0; p < 64; ++p) {
    float2 e = *(const float2*)&epart[((size_t)b * 64 + p) * 16384 + c * 128 + d0];
    s.x += e.x; s.y += e.y;
  }
  float mn = fminf(s.x, s.y);
#pragma unroll
  for (int off = 1; off < 64; off <<= 1) mn = fminf(mn, __shfl_xor(mn, off));
  const float p0 = expf(mn - s.x);
  const float p1 = expf(mn - s.y);
  float tot = p0 + p1;
#pragma unroll
  for (int off = 1; off < 64; off <<= 1) tot += __shfl_xor(tot, off);
  const float inv = 1.f / tot;
  const float a0 = p0 * inv, a1 = p1 * inv;

  const float2 bvv = *(const float2*)&bv[d0];
  float ob = a0 * bvv.x + a1 * bvv.y;
#pragma unroll
  for (int off = 1; off < 64; off <<= 1) ob += __shfl_xor(ob, off);
  if (lane == 0) outbb[b * 128 + c] = ob;

  As[wid][d0] = a0;
  As[wid][d0 + 1] = a1;   // wave-local write->read, lockstep-safe
  float m0 = 0.f, m1 = 0.f;
#pragma unroll 4
  for (int d = 0; d < 128; ++d) {
    const float a = As[wid][d];
    const float2 wv = *(const float2*)&Wv[d * 128 + d0];
    m0 = fmaf(a, wv.x, m0);
    m1 = fmaf(a, wv.y, m1);
  }
  *(float2*)&Mbuf[(size_t)b * 16384 + c * 128 + d0] = make_float2(m0, m1);
}

// ---------------- Kernel 3: out = M @ X + ob, plain bf16 MFMA --------------
// grid (128 n-tiles, 8 b), 256 thr = 4 waves (2x2 of 64x64). K=128.
__global__ __launch_bounds__(256) void k_out(
    const float* __restrict__ x, const float* __restrict__ Mbuf,
    const float* __restrict__ outbb, float* __restrict__ out) {
  __shared__ unsigned short Ms[128 * 40];
  __shared__ unsigned short Xs[128 * 40];
  const int t = threadIdx.x;
  const int nt = blockIdx.x, b = blockIdx.y;
  const int wid = t >> 6, lane = t & 63;
  const int wr = wid >> 1, wc = wid & 1;
  const int lrow = lane & 15, lkb = lane >> 4;
  const int am = t >> 1, ak0 = (t & 1) * 16;
  const int xkl = (t >> 5) * 4;
  const int xc0 = (t & 31) * 4;

  const float* xb = x + ((size_t)b << 21);
  const float* Mb = Mbuf + (size_t)b * 16384;
  float* ob = out + ((size_t)b << 21);

  f32x4 acc[4][4];
#pragma unroll
  for (int m = 0; m < 4; ++m)
#pragma unroll
    for (int n = 0; n < 4; ++n) acc[m][n] = (f32x4){0.f, 0.f, 0.f, 0.f};

  for (int step = 0; step < 4; ++step) {
    const int kk = step * 32;
    {
      float w[16];
      *(float4*)&w[0]  = *(const float4*)&Mb[am * 128 + kk + ak0];
      *(float4*)&w[4]  = *(const float4*)&Mb[am * 128 + kk + ak0 + 4];
      *(float4*)&w[8]  = *(const float4*)&Mb[am * 128 + kk + ak0 + 8];
      *(float4*)&w[12] = *(const float4*)&Mb[am * 128 + kk + ak0 + 12];
      unsigned short hs[16];
#pragma unroll
      for (int i = 0; i < 16; ++i) hs[i] = f2bf(w[i]);
      *(uint4*)&Ms[am * 40 + ak0]     = *(uint4*)&hs[0];
      *(uint4*)&Ms[am * 40 + ak0 + 8] = *(uint4*)&hs[8];
    }
#pragma unroll
    for (int q = 0; q < 4; ++q) {
      const int kl = xkl + q;
      float4 v = *(const float4*)&xb[(size_t)(kk + kl) * 16384 + nt * 128 + xc0];
      Xs[(xc0 + 0) * 40 + kl] = f2bf(v.x);
      Xs[(xc0 + 1) * 40 + kl] = f2bf(v.y);
      Xs[(xc0 + 2) * 40 + kl] = f2bf(v.z);
      Xs[(xc0 + 3) * 40 + kl] = f2bf(v.w);
    }
    __syncthreads();
    s16x8 af[4], bf[4];
#pragma unroll
    for (int m = 0; m < 4; ++m)
      af[m] = *(const s16x8*)&Ms[(wr * 64 + m * 16 + lrow) * 40 + lkb * 8];
#pragma unroll
    for (int n = 0; n < 4; ++n)
      bf[n] = *(const s16x8*)&Xs[(wc * 64 + n * 16 + lrow) * 40 + lkb * 8];
#pragma unroll
    for (int m = 0; m < 4; ++m)
#pragma unroll
      for (int n = 0; n < 4; ++n)
        acc[m][n] = __builtin_amdgcn_mfma_f32_16x16x32_bf16(af[m], bf[n], acc[m][n], 0, 0, 0);
    __syncthreads();
  }
#pragma unroll
  for (int m = 0; m < 4; ++m) {
    const int r0 = wr * 64 + m * 16 + (lane >> 4) * 4;
#pragma unroll
    for (int n = 0; n < 4; ++n) {
      const int gc = nt * 128 + wc * 64 + n * 16 + (lane & 15);
#pragma unroll
      for (int i = 0; i < 4; ++i) {
        const int row = r0 + i;
        ob[(size_t)row * 16384 + gc] = acc[m][n][i] + outbb[b * 128 + row];
      }
    }
  }
}

// ---------------------------------------------------------------------------
extern "C" void kernel_launch(void* const* d_in, const int* in_sizes, int n_in,
                              void* d_out, int out_size, void* d_ws, size_t ws_size,
                              hipStream_t stream) {
  const float* x  = (const float*)d_in[0];
  const float* Wq = (const float*)d_in[1];
  const float* bq = (const float*)d_in[2];
  const float* Wk = (const float*)d_in[3];
  const float* bk = (const float*)d_in[4];
  const float* Wv = (const float*)d_in[5];
  const float* bv = (const float*)d_in[6];
  float* out = (float*)d_out;
  char* ws = (char*)d_ws;

  float* epart = (float*)ws;                               // 32 MiB
  float* Mbuf  = (float*)(ws + 33554432);                  // 512 KiB
  float* outbb = (float*)(ws + 34078720);                  // 4 KiB
  unsigned short* Wth = (unsigned short*)(ws + 34082816);  // 256 KiB
  unsigned short* Wtl = (unsigned short*)(ws + 34344960);  // 256 KiB

  hipLaunchKernelGGL(k_prep, dim3(128), dim3(256), 0, stream, Wq, Wk, Wth, Wtl);
  hipLaunchKernelGGL(k_conv_energy, dim3(64, 8), dim3(256), 0, stream,
                     x, Wth, Wtl, bq, bk, epart);
  hipLaunchKernelGGL(k_softmax_M, dim3(256), dim3(256), 0, stream,
                     epart, Wv, bv, Mbuf, outbb);
  hipLaunchKernelGGL(k_out, dim3(128, 8), dim3(256), 0, stream,
                     x, Mbuf, outbb, out);
}

// Round 8
// 87.012 us; speedup vs baseline: 1.3957x; 1.0070x over previous
//
#include <hip/hip_runtime.h>
#include <math.h>

// ---------------------------------------------------------------------------
// CAM module, fused MFMA version (hi/lo-bf16 q/k/energy path — R3 numerics).
//   k_prep:        [Wq;Wk] -> tiled hi/lo bf16, fragment-coalesced layout
//   k_conv_energy: C=[Wq;Wk]@P per 64-col tile (split-bf16, 3 MFMA/frag)
//                  A fragments global->VGPR, PING-PONG double-buffered across
//                  fully-unrolled K-steps (loads overlap MFMAs);
//                  B tile LDS double-buffer, conflict-free staging writes;
//                  -> repack C+bias to hi/lo bf16 LDS (XOR swizzle)
//                  -> epart[b][nt] = q_tile @ k_tile^T  (q/k never hit HBM)
//   k_softmax_M:   reduce 64 partials, softmax(rowmin-e), M=A@Wv, ob=A@bv
//   k_out:         out = M @ X + ob   (plain bf16 MFMA, HBM-bound)
// Numerics: fp16/bf16-RTN on q/k FAILS (R4: 0.203) — needs hi/lo split.
// R5 lesson: loop-carried prefetch ARRAYS in a rolled loop get demoted to
// LDS — full unroll makes indices constant, keeps them in VGPRs.
// R6 lesson: no pointer arrays initialized from __shared__ (addrspacecast).
// ---------------------------------------------------------------------------

typedef float f32x4 __attribute__((ext_vector_type(4)));
typedef short s16x8 __attribute__((ext_vector_type(8)));

__device__ __forceinline__ unsigned short f2bf(float f) {
  union { float f; unsigned u; } v; v.f = f;
  unsigned r = v.u + 0x7FFFu + ((v.u >> 16) & 1u);
  return (unsigned short)(r >> 16);
}
__device__ __forceinline__ float bf2f(unsigned short h) {
  union { unsigned u; float f; } v; v.u = ((unsigned)h) << 16;
  return v.f;
}
__device__ __forceinline__ unsigned pack2(unsigned short a, unsigned short b) {
  return (unsigned)a | ((unsigned)b << 16);
}

// ---------------- Kernel 0: W -> tiled hi/lo bf16 --------------------------
// Wt[step][row][koff], step = k/32; 16*256*32 u16 per plane. grid 128x256.
__global__ __launch_bounds__(256) void k_prep(
    const float* __restrict__ Wq, const float* __restrict__ Wk,
    unsigned short* __restrict__ Wth, unsigned short* __restrict__ Wtl) {
  const int f = (blockIdx.x * 256 + threadIdx.x) * 4;
  const int row = f >> 9;
  const int k   = f & 511;
  const float* src = (row < 128) ? &Wq[row * 512 + k] : &Wk[(row - 128) * 512 + k];
  float4 v = *(const float4*)src;
  unsigned short h0 = f2bf(v.x), h1 = f2bf(v.y), h2 = f2bf(v.z), h3 = f2bf(v.w);
  unsigned short l0 = f2bf(v.x - bf2f(h0)), l1 = f2bf(v.y - bf2f(h1));
  unsigned short l2 = f2bf(v.z - bf2f(h2)), l3 = f2bf(v.w - bf2f(h3));
  const int di = (k >> 5) * 8192 + row * 32 + (k & 31);
  *(ushort4*)&Wth[di] = make_ushort4(h0, h1, h2, h3);
  *(ushort4*)&Wtl[di] = make_ushort4(l0, l1, l2, l3);
}

// ---------------- Kernel 1: fused conv + energy partial --------------------
// grid (64 nt, 8 b), 256 thr = 4 waves. Tile rows 0-255 (q:0-127,k:128-255),
// cols nt*64..+63, K=512 in 16 fully-unrolled steps of 32 (split-bf16).
__global__ __launch_bounds__(256, 2) void k_conv_energy(
    const float* __restrict__ x,
    const unsigned short* __restrict__ Wth, const unsigned short* __restrict__ Wtl,
    const float* __restrict__ bq, const float* __restrict__ bk,
    float* __restrict__ epart) {
  __shared__ unsigned short LDS[32768];   // 64 KiB, unioned across phases
  // conv phase: B double-buffer at u16 offsets {0,2560} and {5120,7680}
  // energy phase:
  unsigned short* Th = LDS;               // 256*64 (hi)
  unsigned short* Tl = LDS + 16384;       // 256*64 (lo)

  const int t = threadIdx.x;
  const int nt = blockIdx.x, b = blockIdx.y;
  const int w = t >> 6, lane = t & 63;
  const int lrow = lane & 15, lkb = lane >> 4;

  // B staging map: pp=(ci_l,kh); thread i=t&15 stages output cols i+16g.
  const int pp = t >> 4;
  const int ci_l = pp >> 1, kh = pp & 1;
  const int i16 = t & 15;
  const int klb = ci_l * 4 + kh * 2;
  const float* xb = x + ((size_t)b << 21);
  // x address for output col n: xb + ch*16384 + (2nt+kh)*128 + 2n
  const float* xrow = xb + (size_t)ci_l * 16384 + (2 * nt + kh) * 128 + 2 * i16;

  f32x4 acc[4][4];
#pragma unroll
  for (int m = 0; m < 4; ++m)
#pragma unroll
    for (int n = 0; n < 4; ++n) acc[m][n] = (f32x4){0.f, 0.f, 0.f, 0.f};

  // A fragment ping-pong registers (constant-indexed under full unroll)
  s16x8 pfh[2][4], pfl[2][4];
  const int aoff = (w * 64 + lrow) * 32 + lkb * 8;  // +m*16*32 per fragment

  // -------- prologue: A frags step 0, B tile step 0 -----------------------
#pragma unroll
  for (int m = 0; m < 4; ++m) {
    pfh[0][m] = *(const s16x8*)&Wth[aoff + m * 512];
    pfl[0][m] = *(const s16x8*)&Wtl[aoff + m * 512];
  }
  {
#pragma unroll
    for (int g = 0; g < 4; ++g) {
      const int n = i16 + 16 * g;
      float2 v = *(const float2*)&xrow[32 * g];
      unsigned short hx = f2bf(v.x), hy = f2bf(v.y);
      *(unsigned*)&LDS[n * 40 + klb]        = pack2(hx, hy);
      *(unsigned*)&LDS[2560 + n * 40 + klb] = pack2(f2bf(v.x - bf2f(hx)),
                                                    f2bf(v.y - bf2f(hy)));
    }
  }
  __syncthreads();

#pragma unroll
  for (int step = 0; step < 16; ++step) {
    const int cb = step & 1;
    // ---- prefetch A frags for step+1 (fly during this step's MFMAs) ----
    if (step < 15) {
      const unsigned short* Wh_n = Wth + (step + 1) * 8192;
      const unsigned short* Wl_n = Wtl + (step + 1) * 8192;
#pragma unroll
      for (int m = 0; m < 4; ++m) {
        pfh[cb ^ 1][m] = *(const s16x8*)&Wh_n[aoff + m * 512];
        pfl[cb ^ 1][m] = *(const s16x8*)&Wl_n[aoff + m * 512];
      }
    }
    // ---- prefetch x for step+1 ----
    float2 pv0, pv1, pv2, pv3;
    if (step < 15) {
      const float* xr = xrow + (size_t)(step + 1) * 8 * 16384;
      pv0 = *(const float2*)&xr[0];
      pv1 = *(const float2*)&xr[32];
      pv2 = *(const float2*)&xr[64];
      pv3 = *(const float2*)&xr[96];
    }
    // ---- B fragments from LDS buffer[cb] ----
    const unsigned short* Bh = LDS + cb * 5120;
    const unsigned short* Bl = Bh + 2560;
    s16x8 bfh[4], bfl[4];
#pragma unroll
    for (int nf = 0; nf < 4; ++nf) {
      const int bidx = (nf * 16 + lrow) * 40 + lkb * 8;
      bfh[nf] = *(const s16x8*)&Bh[bidx];
      bfl[nf] = *(const s16x8*)&Bl[bidx];
    }
    // ---- MFMA (A from ping-pong regs) ----
#pragma unroll
    for (int m = 0; m < 4; ++m)
#pragma unroll
      for (int n = 0; n < 4; ++n) {
        acc[m][n] = __builtin_amdgcn_mfma_f32_16x16x32_bf16(pfh[cb][m], bfh[n], acc[m][n], 0, 0, 0);
        acc[m][n] = __builtin_amdgcn_mfma_f32_16x16x32_bf16(pfh[cb][m], bfl[n], acc[m][n], 0, 0, 0);
        acc[m][n] = __builtin_amdgcn_mfma_f32_16x16x32_bf16(pfl[cb][m], bfh[n], acc[m][n], 0, 0, 0);
      }
    // ---- convert + write B for step+1 into buffer[cb^1] ----
    if (step < 15) {
      unsigned short* Nh = LDS + (cb ^ 1) * 5120;
      unsigned short* Nl = Nh + 2560;
      {
        const int n = i16;
        unsigned short hx = f2bf(pv0.x), hy = f2bf(pv0.y);
        *(unsigned*)&Nh[n * 40 + klb] = pack2(hx, hy);
        *(unsigned*)&Nl[n * 40 + klb] = pack2(f2bf(pv0.x - bf2f(hx)), f2bf(pv0.y - bf2f(hy)));
      }
      {
        const int n = i16 + 16;
        unsigned short hx = f2bf(pv1.x), hy = f2bf(pv1.y);
        *(unsigned*)&Nh[n * 40 + klb] = pack2(hx, hy);
        *(unsigned*)&Nl[n * 40 + klb] = pack2(f2bf(pv1.x - bf2f(hx)), f2bf(pv1.y - bf2f(hy)));
      }
      {
        const int n = i16 + 32;
        unsigned short hx = f2bf(pv2.x), hy = f2bf(pv2.y);
        *(unsigned*)&Nh[n * 40 + klb] = pack2(hx, hy);
        *(unsigned*)&Nl[n * 40 + klb] = pack2(f2bf(pv2.x - bf2f(hx)), f2bf(pv2.y - bf2f(hy)));
      }
      {
        const int n = i16 + 48;
        unsigned short hx = f2bf(pv3.x), hy = f2bf(pv3.y);
        *(unsigned*)&Nh[n * 40 + klb] = pack2(hx, hy);
        *(unsigned*)&Nl[n * 40 + klb] = pack2(f2bf(pv3.x - bf2f(hx)), f2bf(pv3.y - bf2f(hy)));
      }
    }
    __syncthreads();
  }

  // ---- phase 2: repack C+bias -> hi/lo bf16 LDS tile, XOR-swizzled -------
  const float* biasp = (w < 2) ? bq : bk;
  const int rb = (w & 1) * 64;
  float biasr[16];
#pragma unroll
  for (int m = 0; m < 4; ++m)
#pragma unroll
    for (int i = 0; i < 4; ++i)
      biasr[m * 4 + i] = biasp[rb + m * 16 + (lane >> 4) * 4 + i];

#pragma unroll
  for (int m = 0; m < 4; ++m) {
    const int r0 = w * 64 + m * 16 + (lane >> 4) * 4;
#pragma unroll
    for (int n = 0; n < 4; ++n) {
      const int c = n * 16 + lrow;
      const int c8 = c >> 3, c7 = c & 7;
#pragma unroll
      for (int i = 0; i < 4; ++i) {
        const int r = r0 + i;
        const float vv = acc[m][n][i] + biasr[m * 4 + i];
        const unsigned short h = f2bf(vv);
        const unsigned short l = f2bf(vv - bf2f(h));
        const int ad = r * 64 + (((c8 ^ (r & 7))) << 3) + c7;
        Th[ad] = h;
        Tl[ad] = l;
      }
    }
  }
  __syncthreads();

  // ---- phase 3: energy partial = q_tile(128x64) @ k_tile(128x64)^T --------
  f32x4 e[4][4];
#pragma unroll
  for (int m = 0; m < 4; ++m)
#pragma unroll
    for (int n = 0; n < 4; ++n) e[m][n] = (f32x4){0.f, 0.f, 0.f, 0.f};

  const int mrow0 = (w >> 1) * 64;       // q-half rows (0 or 64)
  const int nrow0 = 128 + (w & 1) * 64;  // k-half rows
#pragma unroll
  for (int ks = 0; ks < 2; ++ks) {
    const int c8 = ks * 4 + lkb;
    s16x8 qh[4], ql[4], kh8[4], kl8[4];
#pragma unroll
    for (int m = 0; m < 4; ++m) {
      const int r = mrow0 + m * 16 + lrow;
      const int ad = r * 64 + ((c8 ^ (r & 7)) << 3);
      qh[m] = *(const s16x8*)&Th[ad];
      ql[m] = *(const s16x8*)&Tl[ad];
    }
#pragma unroll
    for (int n = 0; n < 4; ++n) {
      const int r = nrow0 + n * 16 + lrow;
      const int ad = r * 64 + ((c8 ^ (r & 7)) << 3);
      kh8[n] = *(const s16x8*)&Th[ad];
      kl8[n] = *(const s16x8*)&Tl[ad];
    }
#pragma unroll
    for (int m = 0; m < 4; ++m)
#pragma unroll
      for (int n = 0; n < 4; ++n) {
        e[m][n] = __builtin_amdgcn_mfma_f32_16x16x32_bf16(qh[m], kh8[n], e[m][n], 0, 0, 0);
        e[m][n] = __builtin_amdgcn_mfma_f32_16x16x32_bf16(qh[m], kl8[n], e[m][n], 0, 0, 0);
        e[m][n] = __builtin_amdgcn_mfma_f32_16x16x32_bf16(ql[m], kh8[n], e[m][n], 0, 0, 0);
      }
  }
  float* ep = epart + ((size_t)b * 64 + nt) * 16384;
#pragma unroll
  for (int m = 0; m < 4; ++m) {
    const int qr = (w >> 1) * 64 + m * 16 + (lane >> 4) * 4;
#pragma unroll
    for (int n = 0; n < 4; ++n) {
      const int kr = (w & 1) * 64 + n * 16 + lrow;
#pragma unroll
      for (int i = 0; i < 4; ++i) ep[(size_t)(qr + i) * 128 + kr] = e[m][n][i];
    }
  }
}

// ---------------- Kernel 2: reduce + softmax + M = A@Wv, ob = A@bv ---------
// wave per row c. grid(256): b = blk>>5, c = (blk&31)*4 + wid. 256 thr.
__global__ __launch_bounds__(256) void k_softmax_M(
    const float* __restrict__ epart, const float* __restrict__ Wv,
    const float* __restrict__ bv, float* __restrict__ Mbuf,
    float* __restrict__ outbb) {
  __shared__ float As[4][128];
  const int t = threadIdx.x;
  const int wid = t >> 6, lane = t & 63;
  const int b = blockIdx.x >> 5;
  const int c = (blockIdx.x & 31) * 4 + wid;
  const int d0 = lane * 2;

  float2 s = make_float2(0.f, 0.f);
#pragma unroll 4
  for (int p = 0; p < 64; ++p) {
    float2 e = *(const float2*)&epart[((size_t)b * 64 + p) * 16384 + c * 128 + d0];
    s.x += e.x; s.y += e.y;
  }
  float mn = fminf(s.x, s.y);
#pragma unroll
  for (int off = 1; off < 64; off <<= 1) mn = fminf(mn, __shfl_xor(mn, off));
  const float p0 = expf(mn - s.x);
  const float p1 = expf(mn - s.y);
  float tot = p0 + p1;
#pragma unroll
  for (int off = 1; off < 64; off <<= 1) tot += __shfl_xor(tot, off);
  const float inv = 1.f / tot;
  const float a0 = p0 * inv, a1 = p1 * inv;

  const float2 bvv = *(const float2*)&bv[d0];
  float ob = a0 * bvv.x + a1 * bvv.y;
#pragma unroll
  for (int off = 1; off < 64; off <<= 1) ob += __shfl_xor(ob, off);
  if (lane == 0) outbb[b * 128 + c] = ob;

  As[wid][d0] = a0;
  As[wid][d0 + 1] = a1;   // wave-local write->read, lockstep-safe
  float m0 = 0.f, m1 = 0.f;
#pragma unroll 4
  for (int d = 0; d < 128; ++d) {
    const float a = As[wid][d];
    const float2 wv = *(const float2*)&Wv[d * 128 + d0];
    m0 = fmaf(a, wv.x, m0);
    m1 = fmaf(a, wv.y, m1);
  }
  *(float2*)&Mbuf[(size_t)b * 16384 + c * 128 + d0] = make_float2(m0, m1);
}

// ---------------- Kernel 3: out = M @ X + ob, plain bf16 MFMA --------------
// grid (128 n-tiles, 8 b), 256 thr = 4 waves (2x2 of 64x64). K=128.
__global__ __launch_bounds__(256) void k_out(
    const float* __restrict__ x, const float* __restrict__ Mbuf,
    const float* __restrict__ outbb, float* __restrict__ out) {
  __shared__ unsigned short Ms[128 * 40];
  __shared__ unsigned short Xs[128 * 40];
  const int t = threadIdx.x;
  const int nt = blockIdx.x, b = blockIdx.y;
  const int wid = t >> 6, lane = t & 63;
  const int wr = wid >> 1, wc = wid & 1;
  const int lrow = lane & 15, lkb = lane >> 4;
  const int am = t >> 1, ak0 = (t & 1) * 16;
  const int xkl = (t >> 5) * 4;
  const int xc0 = (t & 31) * 4;

  const float* xb = x + ((size_t)b << 21);
  const float* Mb = Mbuf + (size_t)b * 16384;
  float* ob = out + ((size_t)b << 21);

  f32x4 acc[4][4];
#pragma unroll
  for (int m = 0; m < 4; ++m)
#pragma unroll
    for (int n = 0; n < 4; ++n) acc[m][n] = (f32x4){0.f, 0.f, 0.f, 0.f};

  for (int step = 0; step < 4; ++step) {
    const int kk = step * 32;
    {
      float w[16];
      *(float4*)&w[0]  = *(const float4*)&Mb[am * 128 + kk + ak0];
      *(float4*)&w[4]  = *(const float4*)&Mb[am * 128 + kk + ak0 + 4];
      *(float4*)&w[8]  = *(const float4*)&Mb[am * 128 + kk + ak0 + 8];
      *(float4*)&w[12] = *(const float4*)&Mb[am * 128 + kk + ak0 + 12];
      unsigned short hs[16];
#pragma unroll
      for (int i = 0; i < 16; ++i) hs[i] = f2bf(w[i]);
      *(uint4*)&Ms[am * 40 + ak0]     = *(uint4*)&hs[0];
      *(uint4*)&Ms[am * 40 + ak0 + 8] = *(uint4*)&hs[8];
    }
#pragma unroll
    for (int q = 0; q < 4; ++q) {
      const int kl = xkl + q;
      float4 v = *(const float4*)&xb[(size_t)(kk + kl) * 16384 + nt * 128 + xc0];
      Xs[(xc0 + 0) * 40 + kl] = f2bf(v.x);
      Xs[(xc0 + 1) * 40 + kl] = f2bf(v.y);
      Xs[(xc0 + 2) * 40 + kl] = f2bf(v.z);
      Xs[(xc0 + 3) * 40 + kl] = f2bf(v.w);
    }
    __syncthreads();
    s16x8 af[4], bf[4];
#pragma unroll
    for (int m = 0; m < 4; ++m)
      af[m] = *(const s16x8*)&Ms[(wr * 64 + m * 16 + lrow) * 40 + lkb * 8];
#pragma unroll
    for (int n = 0; n < 4; ++n)
      bf[n] = *(const s16x8*)&Xs[(wc * 64 + n * 16 + lrow) * 40 + lkb * 8];
#pragma unroll
    for (int m = 0; m < 4; ++m)
#pragma unroll
      for (int n = 0; n < 4; ++n)
        acc[m][n] = __builtin_amdgcn_mfma_f32_16x16x32_bf16(af[m], bf[n], acc[m][n], 0, 0, 0);
    __syncthreads();
  }
#pragma unroll
  for (int m = 0; m < 4; ++m) {
    const int r0 = wr * 64 + m * 16 + (lane >> 4) * 4;
#pragma unroll
    for (int n = 0; n < 4; ++n) {
      const int gc = nt * 128 + wc * 64 + n * 16 + (lane & 15);
#pragma unroll
      for (int i = 0; i < 4; ++i) {
        const int row = r0 + i;
        ob[(size_t)row * 16384 + gc] = acc[m][n][i] + outbb[b * 128 + row];
      }
    }
  }
}

// ---------------------------------------------------------------------------
extern "C" void kernel_launch(void* const* d_in, const int* in_sizes, int n_in,
                              void* d_out, int out_size, void* d_ws, size_t ws_size,
                              hipStream_t stream) {
  const float* x  = (const float*)d_in[0];
  const float* Wq = (const float*)d_in[1];
  const float* bq = (const float*)d_in[2];
  const float* Wk = (const float*)d_in[3];
  const float* bk = (const float*)d_in[4];
  const float* Wv = (const float*)d_in[5];
  const float* bv = (const float*)d_in[6];
  float* out = (float*)d_out;
  char* ws = (char*)d_ws;

  float* epart = (float*)ws;                               // 32 MiB
  float* Mbuf  = (float*)(ws + 33554432);                  // 512 KiB
  float* outbb = (float*)(ws + 34078720);                  // 4 KiB
  unsigned short* Wth = (unsigned short*)(ws + 34082816);  // 256 KiB
  unsigned short* Wtl = (unsigned short*)(ws + 34344960);  // 256 KiB

  hipLaunchKernelGGL(k_prep, dim3(128), dim3(256), 0, stream, Wq, Wk, Wth, Wtl);
  hipLaunchKernelGGL(k_conv_energy, dim3(64, 8), dim3(256), 0, stream,
                     x, Wth, Wtl, bq, bk, epart);
  hipLaunchKernelGGL(k_softmax_M, dim3(256), dim3(256), 0, stream,
                     epart, Wv, bv, Mbuf, outbb);
  hipLaunchKernelGGL(k_out, dim3(128, 8), dim3(256), 0, stream,
                     x, Mbuf, outbb, out);
}